// Round 7
// baseline (636.566 us; speedup 1.0000x reference)
//
#include <hip/hip_runtime.h>
#include <stdint.h>

#define D_EMB 128
#define HIDDEN 64
#define PACK_SCALE 1024.0f
#define INV_PACK (1.0f/1024.0f)
#define PN 32   // nodes per proj block

typedef __attribute__((ext_vector_type(4))) float f32x4;

__device__ __forceinline__ uint32_t rotl32(uint32_t x, int r) {
    return (x << r) | (x >> (32 - r));
}

// Bit-exact JAX threefry2x32, PARTITIONABLE path (default since jax 0.4.36).
// key = jax.random.key(42) -> (k1,k2) = (0,42); draw = final_x0 ^ final_x1 of
// counts (0, e).
__device__ __forceinline__ uint32_t jax_threefry_bits_part(uint32_t e) {
    const uint32_t ks0 = 0u;
    const uint32_t ks1 = 42u;
    const uint32_t ks2 = 0x1BD11BDAu ^ 0u ^ 42u;
    uint32_t x0 = 0u + ks0;
    uint32_t x1 = e + ks1;
#define TF_R(r) { x0 += x1; x1 = rotl32(x1, (r)); x1 ^= x0; }
    TF_R(13) TF_R(15) TF_R(26) TF_R(6)
    x0 += ks1; x1 += ks2 + 1u;
    TF_R(17) TF_R(29) TF_R(16) TF_R(24)
    x0 += ks2; x1 += ks0 + 2u;
    TF_R(13) TF_R(15) TF_R(26) TF_R(6)
    x0 += ks0; x1 += ks1 + 3u;
    TF_R(17) TF_R(29) TF_R(16) TF_R(24)
    x0 += ks1; x1 += ks2 + 4u;
    TF_R(13) TF_R(15) TF_R(26) TF_R(6)
    x0 += ks2; x1 += ks0 + 5u;
#undef TF_R
    return x0 ^ x1;
}

// Per-edge MLP logit -> concrete-sample gate value v in (0,1).
__device__ __forceinline__ float edge_gate_value(
    const float* __restrict__ Pcat, const float* __restrict__ w2s, float b2v,
    int c, int r, int e) {
    const float4* p1 = (const float4*)(Pcat + (size_t)c * (2 * HIDDEN));
    const float4* p2 = (const float4*)(Pcat + (size_t)r * (2 * HIDDEN) + HIDDEN);
    const float4* w4 = (const float4*)w2s;
    float la = b2v;
#pragma unroll
    for (int k = 0; k < HIDDEN / 4; k++) {
        float4 a = p1[k];
        float4 b = p2[k];
        float4 w = w4[k];
        la += fmaxf(a.x + b.x, 0.0f) * w.x + fmaxf(a.y + b.y, 0.0f) * w.y +
              fmaxf(a.z + b.z, 0.0f) * w.z + fmaxf(a.w + b.w, 0.0f) * w.w;
    }
    uint32_t bits = jax_threefry_bits_part((uint32_t)e);
    float u = __uint_as_float((bits >> 9) | 0x3f800000u) - 1.0f;
    // sigmoid(log(u) - log1p(-u) + la) == u / (u + (1-u)*exp(-la))
    return u / (u + (1.0f - u) * __expf(-la));
}

// Fill kernel: one shot, 64B per thread (4x float4 contiguous), nontemporal.
// Replaces the rocclr fillBuffer node (observed size-independent ~245us cost).
__global__ __launch_bounds__(256) void fill_zero_kernel(
    f32x4* __restrict__ out, size_t n4) {
    size_t base = ((size_t)blockIdx.x * 256 + threadIdx.x) * 4;
    f32x4 z = {0.0f, 0.0f, 0.0f, 0.0f};
#pragma unroll
    for (int i = 0; i < 4; i++) {
        size_t idx = base + i;
        if (idx < n4) __builtin_nontemporal_store(z, &out[idx]);
    }
}

// Kernel 1 (proj v3): thread owns one output column, register-tiles 16 nodes,
// so each W1 element is fetched once per 16 nodes (W1 L2 traffic 640->80 MB).
// Pcat[n][0:64] = embed[n] @ W1[:128] + b1 ; Pcat[n][64:128] = embed[n] @ W1[128:]
__global__ __launch_bounds__(256) void node_proj_kernel(
    const float* __restrict__ embed, const float* __restrict__ W1,
    const float* __restrict__ b1, float* __restrict__ Pcat, int N) {
    __shared__ float e_lds[PN][D_EMB];    // 16 KB
    int n0 = blockIdx.x * PN;
    int t = threadIdx.x;
    // cooperative load: PN*32 = 1024 float4s with 256 threads (4 each)
    {
        const float4* src = (const float4*)embed + (size_t)n0 * (D_EMB / 4);
        float4* dst = (float4*)&e_lds[0][0];
        for (int i = t; i < PN * (D_EMB / 4); i += 256) {
            int node = n0 + (i >> 5);
            float4 v = make_float4(0.f, 0.f, 0.f, 0.f);
            if (node < N) v = src[i];
            dst[i] = v;
        }
    }
    __syncthreads();
    int col = t & 127;
    int nset = t >> 7;                    // 0/1 -> nodes nset*16 .. +15
    int half = col >> 6, k = col & 63;
    const float* w = W1 + (size_t)half * D_EMB * HIDDEN + k;
    float bias = (half == 0) ? b1[k] : 0.0f;
    float acc[16];
#pragma unroll
    for (int j = 0; j < 16; j++) acc[j] = bias;
    const int nb = nset * 16;
#pragma unroll 8
    for (int d = 0; d < D_EMB; d++) {
        float wd = w[(size_t)d * HIDDEN];
#pragma unroll
        for (int j = 0; j < 16; j++) acc[j] += e_lds[nb + j][d] * wd;  // LDS broadcast
    }
#pragma unroll
    for (int j = 0; j < 16; j++) {
        int node = n0 + nb + j;
        if (node < N) Pcat[(size_t)node * (2 * HIDDEN) + col] = acc[j];
    }
}

// Kernel 2: per-edge gate value, packed atomic accumulate into out[c*N+r].
// Cell state after this pass: 1024*cnt + sum(v), always >= 1024 for touched.
__global__ __launch_bounds__(256) void edge_scatter_kernel(
    const int* __restrict__ ei, const float* __restrict__ Pcat,
    const float* __restrict__ W2, const float* __restrict__ b2,
    float* __restrict__ out, int E, int N) {
    __shared__ float w2s[HIDDEN];
    if (threadIdx.x < HIDDEN) w2s[threadIdx.x] = W2[threadIdx.x];
    __syncthreads();
    int e = blockIdx.x * blockDim.x + threadIdx.x;
    if (e >= E) return;
    int c = ei[e];
    int r = ei[E + e];
    if ((unsigned)c >= (unsigned)N || (unsigned)r >= (unsigned)N) return;
    float v = edge_gate_value(Pcat, w2s, b2[0], c, r, e);
    atomicAdd(out + (size_t)c * N + r, PACK_SCALE + v);
}

// Kernel 3: single-pass self-synchronizing symmetric finalize.
// States disjoint: 0 = untouched, (0,1024) = finalized, >=1024 = packed.
// Owner (c<=r, or c>r with untouched mirror) writes BOTH cells' finals.
// Races idempotent: finals are a deterministic function of the unique packed
// state; any interleaving (incl. stale cross-XCD reads of the older packed
// state) produces identical bits.
__global__ __launch_bounds__(256) void edge_finalize_kernel(
    const int* __restrict__ ei, float* __restrict__ out, int E, int N) {
    int e = blockIdx.x * blockDim.x + threadIdx.x;
    if (e >= E) return;
    int c = ei[e];
    int r = ei[E + e];
    if ((unsigned)c >= (unsigned)N || (unsigned)r >= (unsigned)N) return;

    size_t own = (size_t)c * N + r;
    size_t mir = (size_t)r * N + c;
    float a = out[own];
    if (a < PACK_SCALE) return;            // duplicate already finalized own cell
    float b = out[mir];
    if (c != r && b > 0.0f && b < PACK_SCALE) return;  // pair mid-finalize by owner

    if (c <= r || b == 0.0f) {             // owner
        float cnt_a = truncf(a * INV_PACK);
        float s_a = a - PACK_SCALE * cnt_a;
        float cnt_b = truncf(b * INV_PACK); // b==0 -> 0,0
        float s_b = b - PACK_SCALE * cnt_b;
        float sum = s_a + s_b;             // c==r: a==b so sum = 2*s_a, correct
        out[own] = cnt_a * 0.5f * sum;
        if (c < r && b != 0.0f) out[mir] = cnt_b * 0.5f * sum;
    }
    // c>r with packed mirror: the mirror edge's owner thread writes both cells.
}

extern "C" void kernel_launch(void* const* d_in, const int* in_sizes, int n_in,
                              void* d_out, int out_size, void* d_ws, size_t ws_size,
                              hipStream_t stream) {
    const float* embed = (const float*)d_in[0];
    const int*   ei    = (const int*)d_in[1];
    const float* W1    = (const float*)d_in[2];
    const float* b1    = (const float*)d_in[3];
    const float* W2    = (const float*)d_in[4];
    const float* b2    = (const float*)d_in[5];
    float* out = (float*)d_out;

    const int N = in_sizes[0] / D_EMB;      // 10000
    const int E = in_sizes[1] / 2;          // 640000

    float* Pcat = (float*)d_ws;             // N*128 floats = 5.12 MB

    // Zero the dense output with our own one-shot wide-store kernel.
    size_t n4 = (size_t)out_size / 4;       // out_size % 4 == 0 (N*N, N even)
    size_t fill_blocks = (n4 + 1023) / 1024;  // 4 float4 per thread, 256 thr
    fill_zero_kernel<<<(uint32_t)fill_blocks, 256, 0, stream>>>((f32x4*)out, n4);

    node_proj_kernel<<<(N + PN - 1) / PN, 256, 0, stream>>>(embed, W1, b1, Pcat, N);

    const int eb = 256;
    const int eg = (E + eb - 1) / eb;
    edge_scatter_kernel<<<eg, eb, 0, stream>>>(ei, Pcat, W2, b2, out, E, N);
    edge_finalize_kernel<<<eg, eb, 0, stream>>>(ei, out, E, N);
}

// Round 8
// 228.360 us; speedup vs baseline: 2.7876x; 2.7876x over previous
//
#include <hip/hip_runtime.h>
#include <stdint.h>

#define D_EMB 128
#define HIDDEN 64
#define PACK_SCALE 1024.0f
#define INV_PACK (1.0f/1024.0f)
#define PN 32   // nodes per proj block

__device__ __forceinline__ uint32_t rotl32(uint32_t x, int r) {
    return (x << r) | (x >> (32 - r));
}

// Bit-exact JAX threefry2x32, PARTITIONABLE path (default since jax 0.4.36).
// key = jax.random.key(42) -> (k1,k2) = (0,42); draw = final_x0 ^ final_x1 of
// counts (0, e).
__device__ __forceinline__ uint32_t jax_threefry_bits_part(uint32_t e) {
    const uint32_t ks0 = 0u;
    const uint32_t ks1 = 42u;
    const uint32_t ks2 = 0x1BD11BDAu ^ 0u ^ 42u;
    uint32_t x0 = 0u + ks0;
    uint32_t x1 = e + ks1;
#define TF_R(r) { x0 += x1; x1 = rotl32(x1, (r)); x1 ^= x0; }
    TF_R(13) TF_R(15) TF_R(26) TF_R(6)
    x0 += ks1; x1 += ks2 + 1u;
    TF_R(17) TF_R(29) TF_R(16) TF_R(24)
    x0 += ks2; x1 += ks0 + 2u;
    TF_R(13) TF_R(15) TF_R(26) TF_R(6)
    x0 += ks0; x1 += ks1 + 3u;
    TF_R(17) TF_R(29) TF_R(16) TF_R(24)
    x0 += ks1; x1 += ks2 + 4u;
    TF_R(13) TF_R(15) TF_R(26) TF_R(6)
    x0 += ks2; x1 += ks0 + 5u;
#undef TF_R
    return x0 ^ x1;
}

// Per-edge MLP logit -> concrete-sample gate value v in (0,1).
__device__ __forceinline__ float edge_gate_value(
    const float* __restrict__ Pcat, const float* __restrict__ w2s, float b2v,
    int c, int r, int e) {
    const float4* p1 = (const float4*)(Pcat + (size_t)c * (2 * HIDDEN));
    const float4* p2 = (const float4*)(Pcat + (size_t)r * (2 * HIDDEN) + HIDDEN);
    const float4* w4 = (const float4*)w2s;
    float la = b2v;
#pragma unroll
    for (int k = 0; k < HIDDEN / 4; k++) {
        float4 a = p1[k];
        float4 b = p2[k];
        float4 w = w4[k];
        la += fmaxf(a.x + b.x, 0.0f) * w.x + fmaxf(a.y + b.y, 0.0f) * w.y +
              fmaxf(a.z + b.z, 0.0f) * w.z + fmaxf(a.w + b.w, 0.0f) * w.w;
    }
    uint32_t bits = jax_threefry_bits_part((uint32_t)e);
    float u = __uint_as_float((bits >> 9) | 0x3f800000u) - 1.0f;
    // sigmoid(log(u) - log1p(-u) + la) == u / (u + (1-u)*exp(-la))
    return u / (u + (1.0f - u) * __expf(-la));
}

// Kernel 1 (proj v3): thread owns one output column, register-tiles 16 nodes,
// so each W1 element is fetched once per 16 nodes (W1 L2 traffic 640->80 MB).
// Pcat[n][0:64] = embed[n] @ W1[:128] + b1 ; Pcat[n][64:128] = embed[n] @ W1[128:]
__global__ __launch_bounds__(256) void node_proj_kernel(
    const float* __restrict__ embed, const float* __restrict__ W1,
    const float* __restrict__ b1, float* __restrict__ Pcat, int N) {
    __shared__ float e_lds[PN][D_EMB];    // 16 KB
    int n0 = blockIdx.x * PN;
    int t = threadIdx.x;
    // cooperative load: PN*32 = 1024 float4s with 256 threads (4 each)
    {
        const float4* src = (const float4*)embed + (size_t)n0 * (D_EMB / 4);
        float4* dst = (float4*)&e_lds[0][0];
        for (int i = t; i < PN * (D_EMB / 4); i += 256) {
            int node = n0 + (i >> 5);
            float4 v = make_float4(0.f, 0.f, 0.f, 0.f);
            if (node < N) v = src[i];
            dst[i] = v;
        }
    }
    __syncthreads();
    int col = t & 127;
    int nset = t >> 7;                    // 0/1 -> nodes nset*16 .. +15
    int half = col >> 6, k = col & 63;
    const float* w = W1 + (size_t)half * D_EMB * HIDDEN + k;
    float bias = (half == 0) ? b1[k] : 0.0f;
    float acc[16];
#pragma unroll
    for (int j = 0; j < 16; j++) acc[j] = bias;
    const int nb = nset * 16;
#pragma unroll 8
    for (int d = 0; d < D_EMB; d++) {
        float wd = w[(size_t)d * HIDDEN];
#pragma unroll
        for (int j = 0; j < 16; j++) acc[j] += e_lds[nb + j][d] * wd;  // LDS broadcast
    }
#pragma unroll
    for (int j = 0; j < 16; j++) {
        int node = n0 + nb + j;
        if (node < N) Pcat[(size_t)node * (2 * HIDDEN) + col] = acc[j];
    }
}

// Kernel 2: per-edge gate value, packed atomic accumulate into out[c*N+r].
// Cell state after this pass: 1024*cnt + sum(v), always >= 1024 for touched.
__global__ __launch_bounds__(256) void edge_scatter_kernel(
    const int* __restrict__ ei, const float* __restrict__ Pcat,
    const float* __restrict__ W2, const float* __restrict__ b2,
    float* __restrict__ out, int E, int N) {
    __shared__ float w2s[HIDDEN];
    if (threadIdx.x < HIDDEN) w2s[threadIdx.x] = W2[threadIdx.x];
    __syncthreads();
    int e = blockIdx.x * blockDim.x + threadIdx.x;
    if (e >= E) return;
    int c = ei[e];
    int r = ei[E + e];
    if ((unsigned)c >= (unsigned)N || (unsigned)r >= (unsigned)N) return;
    float v = edge_gate_value(Pcat, w2s, b2[0], c, r, e);
    atomicAdd(out + (size_t)c * N + r, PACK_SCALE + v);
}

// Kernel 3: single-pass self-synchronizing symmetric finalize.
// States disjoint: 0 = untouched, (0,1024) = finalized, >=1024 = packed.
// Owner (c<=r, or c>r with untouched mirror) writes BOTH cells' finals.
// Races idempotent: finals are a deterministic function of the unique packed
// state; any interleaving (incl. stale cross-XCD reads of the older packed
// state) produces identical bits.
__global__ __launch_bounds__(256) void edge_finalize_kernel(
    const int* __restrict__ ei, float* __restrict__ out, int E, int N) {
    int e = blockIdx.x * blockDim.x + threadIdx.x;
    if (e >= E) return;
    int c = ei[e];
    int r = ei[E + e];
    if ((unsigned)c >= (unsigned)N || (unsigned)r >= (unsigned)N) return;

    size_t own = (size_t)c * N + r;
    size_t mir = (size_t)r * N + c;
    float a = out[own];
    if (a < PACK_SCALE) return;            // duplicate already finalized own cell
    float b = out[mir];
    if (c != r && b > 0.0f && b < PACK_SCALE) return;  // pair mid-finalize by owner

    if (c <= r || b == 0.0f) {             // owner
        float cnt_a = truncf(a * INV_PACK);
        float s_a = a - PACK_SCALE * cnt_a;
        float cnt_b = truncf(b * INV_PACK); // b==0 -> 0,0
        float s_b = b - PACK_SCALE * cnt_b;
        float sum = s_a + s_b;             // c==r: a==b so sum = 2*s_a, correct
        out[own] = cnt_a * 0.5f * sum;
        if (c < r && b != 0.0f) out[mir] = cnt_b * 0.5f * sum;
    }
    // c>r with packed mirror: the mirror edge's owner thread writes both cells.
}

extern "C" void kernel_launch(void* const* d_in, const int* in_sizes, int n_in,
                              void* d_out, int out_size, void* d_ws, size_t ws_size,
                              hipStream_t stream) {
    const float* embed = (const float*)d_in[0];
    const int*   ei    = (const int*)d_in[1];
    const float* W1    = (const float*)d_in[2];
    const float* b1    = (const float*)d_in[3];
    const float* W2    = (const float*)d_in[4];
    const float* b2    = (const float*)d_in[5];
    float* out = (float*)d_out;

    const int N = in_sizes[0] / D_EMB;      // 10000
    const int E = in_sizes[1] / 2;          // 640000

    float* Pcat = (float*)d_ws;             // N*128 floats = 5.12 MB

    // Zero the dense output. rocclr's fill (contiguous 16B/lane) runs at full
    // write BW in the timed graph; hand-rolled variants measured slower
    // (R3: grid-stride 86us; R7: 64B/thread striped+nt = 2.7x write-amp, 510us).
    hipMemsetAsync(d_out, 0, (size_t)out_size * sizeof(float), stream);

    node_proj_kernel<<<(N + PN - 1) / PN, 256, 0, stream>>>(embed, W1, b1, Pcat, N);

    const int eb = 256;
    const int eg = (E + eb - 1) / eb;
    edge_scatter_kernel<<<eg, eb, 0, stream>>>(ei, Pcat, W2, b2, out, E, N);
    edge_finalize_kernel<<<eg, eb, 0, stream>>>(ei, out, E, N);
}